// Round 1
// baseline (394.778 us; speedup 1.0000x reference)
//
#include <hip/hip_runtime.h>

// ---------------------------------------------------------------------------
// GCN layer: out[b][f][t][n] = relu( rsqrt(deg_in[n]) *
//     sum_{e: dst[e]=n} ( rsqrt(deg_out[src[e]]) * x[src[e]] @ W )[b][t][f] + bias[f] )
// Strategy: (1) degrees+CSR, (2) fused transpose+GEMM -> y[n][512] node-major,
//           (3) CSR gather-sum + epilogue + transpose-back.
// ---------------------------------------------------------------------------

extern "C" __global__ void k_zero(int* __restrict__ p, int n) {
  int i = blockIdx.x * blockDim.x + threadIdx.x;
  if (i < n) p[i] = 0;
}

extern "C" __global__ void k_deg(const int* __restrict__ src, const int* __restrict__ dst,
                                 int* __restrict__ deg_out, int* __restrict__ deg_in, int E) {
  int e = blockIdx.x * blockDim.x + threadIdx.x;
  if (e < E) {
    atomicAdd(&deg_out[src[e]], 1);
    atomicAdd(&deg_in[dst[e]], 1);
  }
}

extern "C" __global__ void k_rsqrt(const int* __restrict__ dgo, const int* __restrict__ dgi,
                                   float* __restrict__ rs_out, float* __restrict__ rs_in, int N) {
  int i = blockIdx.x * blockDim.x + threadIdx.x;
  if (i < N) {
    int a = dgo[i] > 1 ? dgo[i] : 1;
    int b = dgi[i] > 1 ? dgi[i] : 1;
    rs_out[i] = rsqrtf((float)a);
    rs_in[i]  = rsqrtf((float)b);
  }
}

extern "C" __global__ __launch_bounds__(1024) void k_scan(const int* __restrict__ deg,
                                                          int* __restrict__ offs, int N) {
  __shared__ int part[1024];
  int tid = threadIdx.x;
  int chunk = (N + 1023) >> 10;
  int lo = tid * chunk;
  int hi = lo + chunk; if (hi > N) hi = N;
  int s = 0;
  for (int i = lo; i < hi; ++i) s += deg[i];
  part[tid] = s;
  __syncthreads();
  for (int off = 1; off < 1024; off <<= 1) {
    int v = part[tid];
    if (tid >= off) v += part[tid - off];
    __syncthreads();
    part[tid] = v;
    __syncthreads();
  }
  int run = (tid > 0) ? part[tid - 1] : 0;
  for (int i = lo; i < hi; ++i) { offs[i] = run; run += deg[i]; }
  if (tid == 1023) offs[N] = part[1023];
}

extern "C" __global__ void k_scatter(const int* __restrict__ src, const int* __restrict__ dst,
                                     const int* __restrict__ offs, int* __restrict__ cursor,
                                     int* __restrict__ csr_src, int E) {
  int e = blockIdx.x * blockDim.x + threadIdx.x;
  if (e < E) {
    int d = dst[e];
    int pos = offs[d] + atomicAdd(&cursor[d], 1);
    csr_src[pos] = src[e];
  }
}

// y[n][(b*4+t)*64 + f] = rs_out[n] * sum_h in_feat[((b*64+h)*4+t)*N + n] * W[h*64+f]
extern "C" __global__ __launch_bounds__(256) void k_transform(
    const float* __restrict__ in_feat, const float* __restrict__ W,
    const float* __restrict__ rs_out, float* __restrict__ y, int N) {
  __shared__ float Wl[4096];
  __shared__ float tile[4096];  // [h=64][n=64]
  int tid = threadIdx.x;
  for (int i = tid; i < 4096; i += 256) Wl[i] = W[i];
  int n0 = blockIdx.x * 64;
  int nq = tid & 15;        // n quad: n = nq*4 .. nq*4+3
  int fq = tid >> 4;        // f quad: f = fq*4 .. fq*4+3
  int lrow = tid >> 6, lcol = tid & 63;
  __syncthreads();

  for (int bt = 0; bt < 8; ++bt) {
    int b = bt >> 2, t = bt & 3;
    // load tile[h][n], channel-major coalesced 256B rows
    #pragma unroll
    for (int i = 0; i < 16; ++i) {
      int h = i * 4 + lrow;
      int n = n0 + lcol;
      float v = 0.0f;
      if (n < N) v = in_feat[(size_t)((b * 64 + h) * 4 + t) * (size_t)N + n];
      tile[h * 64 + lcol] = v;
    }
    __syncthreads();

    float acc[4][4];
    #pragma unroll
    for (int i = 0; i < 4; ++i)
      #pragma unroll
      for (int j = 0; j < 4; ++j) acc[i][j] = 0.0f;

    #pragma unroll 8
    for (int h = 0; h < 64; ++h) {
      float4 a = *(const float4*)&tile[h * 64 + nq * 4];
      float4 w = *(const float4*)&Wl[h * 64 + fq * 4];
      float av[4] = {a.x, a.y, a.z, a.w};
      float wv[4] = {w.x, w.y, w.z, w.w};
      #pragma unroll
      for (int i = 0; i < 4; ++i)
        #pragma unroll
        for (int j = 0; j < 4; ++j)
          acc[i][j] = fmaf(av[i], wv[j], acc[i][j]);
    }

    #pragma unroll
    for (int i = 0; i < 4; ++i) {
      int n = n0 + nq * 4 + i;
      if (n < N) {
        float rs = rs_out[n];
        float4 o;
        o.x = acc[i][0] * rs; o.y = acc[i][1] * rs;
        o.z = acc[i][2] * rs; o.w = acc[i][3] * rs;
        *(float4*)&y[(size_t)n * 512 + bt * 64 + fq * 4] = o;
      }
    }
    __syncthreads();
  }
}

// out[((b*64+f)*4+t)*N + n] = relu( rs_in[n] * sum_{j in CSR(n)} y[csr_src[j]][c] + bias[f] )
extern "C" __global__ __launch_bounds__(256) void k_aggregate(
    const float* __restrict__ y, const int* __restrict__ offs,
    const int* __restrict__ csr_src, const float* __restrict__ rs_in,
    const float* __restrict__ bvec, float* __restrict__ out, int N) {
  __shared__ float agg[32 * 513];  // [node][channel], pad 513 -> conflict-free epilogue
  int tid = threadIdx.x;
  int lane = tid & 63, wave = tid >> 6;
  int n0 = blockIdx.x * 32;

  #pragma unroll
  for (int k = 0; k < 8; ++k) {
    int nl = k * 4 + wave;
    int n = n0 + nl;
    float4 accA = {0.f, 0.f, 0.f, 0.f};
    float4 accB = {0.f, 0.f, 0.f, 0.f};
    if (n < N) {
      int j0 = offs[n], j1 = offs[n + 1];
      int j = j0;
      for (; j + 1 < j1; j += 2) {
        int s0 = csr_src[j], s1 = csr_src[j + 1];
        const float4* r0 = (const float4*)(y + (size_t)s0 * 512);
        const float4* r1 = (const float4*)(y + (size_t)s1 * 512);
        float4 a0 = r0[lane], b0 = r0[64 + lane];
        float4 a1 = r1[lane], b1 = r1[64 + lane];
        accA.x += a0.x + a1.x; accA.y += a0.y + a1.y;
        accA.z += a0.z + a1.z; accA.w += a0.w + a1.w;
        accB.x += b0.x + b1.x; accB.y += b0.y + b1.y;
        accB.z += b0.z + b1.z; accB.w += b0.w + b1.w;
      }
      if (j < j1) {
        int s0 = csr_src[j];
        const float4* r0 = (const float4*)(y + (size_t)s0 * 512);
        float4 a0 = r0[lane], b0 = r0[64 + lane];
        accA.x += a0.x; accA.y += a0.y; accA.z += a0.z; accA.w += a0.w;
        accB.x += b0.x; accB.y += b0.y; accB.z += b0.z; accB.w += b0.w;
      }
    }
    *(float4*)&agg[nl * 513 + lane * 4] = accA;
    *(float4*)&agg[nl * 513 + 256 + lane * 4] = accB;
  }
  __syncthreads();

  // epilogue: scale, bias, relu, transpose-back to channel-major
  int nl = tid & 31;
  int r0 = tid >> 5;  // 0..7
  int n = n0 + nl;
  float rs = (n < N) ? rs_in[n] : 0.0f;
  #pragma unroll 4
  for (int it = 0; it < 64; ++it) {
    int c = it * 8 + r0;          // c = (b*4+t)*64 + f
    float v = agg[nl * 513 + c];
    int f = c & 63, bt = c >> 6;
    int b = bt >> 2, t = bt & 3;
    v = v * rs + bvec[f];
    v = fmaxf(v, 0.0f);
    if (n < N) out[(size_t)((b * 64 + f) * 4 + t) * (size_t)N + n] = v;
  }
}

extern "C" void kernel_launch(void* const* d_in, const int* in_sizes, int n_in,
                              void* d_out, int out_size, void* d_ws, size_t ws_size,
                              hipStream_t stream) {
  const float* in_feat = (const float*)d_in[0];
  const int*   src     = (const int*)d_in[1];
  const int*   dst     = (const int*)d_in[2];
  const float* W       = (const float*)d_in[3];
  const float* bvec    = (const float*)d_in[4];
  float* out = (float*)d_out;

  int N = in_sizes[0] / 512;   // B*H*T = 2*64*4 = 512
  int E = in_sizes[1];

  int A  = (N + 64) & ~63;     // room for N+1 offsets, 64-aligned
  int EA = (E + 63) & ~63;

  int*   deg_out_i = (int*)d_ws;        // [A]
  int*   deg_in_i  = deg_out_i + A;     // [A]
  int*   offs      = deg_in_i + A;      // [A] (N+1 used)
  int*   cursor    = offs + A;          // [A]
  float* rs_out    = (float*)(cursor + A);
  float* rs_in     = rs_out + A;
  int*   csr_src   = (int*)(rs_in + A); // [EA]
  float* y         = (float*)(csr_src + EA); // [N*512]

  int z = 4 * A;  // zero deg_out, deg_in, offs(junk ok), cursor in one go
  hipLaunchKernelGGL(k_zero, dim3((z + 255) / 256), dim3(256), 0, stream, deg_out_i, z);
  hipLaunchKernelGGL(k_deg, dim3((E + 255) / 256), dim3(256), 0, stream,
                     src, dst, deg_out_i, deg_in_i, E);
  hipLaunchKernelGGL(k_rsqrt, dim3((N + 255) / 256), dim3(256), 0, stream,
                     deg_out_i, deg_in_i, rs_out, rs_in, N);
  hipLaunchKernelGGL(k_scan, dim3(1), dim3(1024), 0, stream, deg_in_i, offs, N);
  hipLaunchKernelGGL(k_scatter, dim3((E + 255) / 256), dim3(256), 0, stream,
                     src, dst, offs, cursor, csr_src, E);
  hipLaunchKernelGGL(k_transform, dim3((N + 63) / 64), dim3(256), 0, stream,
                     in_feat, W, rs_out, y, N);
  hipLaunchKernelGGL(k_aggregate, dim3((N + 31) / 32), dim3(256), 0, stream,
                     y, offs, csr_src, rs_in, bvec, out, N);
}